// Round 13
// baseline (62.359 us; speedup 1.0000x reference)
//
#include <hip/hip_runtime.h>
#include <cstddef>

#define BB 64
#define MM 5
#define NN 1000
#define DD 128
#define HH 8
#define KSZ 16
#define NT 8         // k2 tiles per (b,h), 125 n each
#define TN 125
#define NC3 8        // k3 chunks per b
#define CH3 125      // k3 chunk size
#define INV_SQRT_D 0.08838834764831845f

// k2 LDS tile regions (bytes) within one buffer
#define K2_KOFF 0
#define K2_VOFF 8192
#define K2_NOFF 16384
#define K2_POFF 36864
#define K2_BUF  37376

typedef __attribute__((address_space(1))) const void gconst_t;
typedef __attribute__((address_space(3))) void lds_t;
#define GLD16(src, dst) __builtin_amdgcn_global_load_lds((gconst_t*)(src), (lds_t*)(dst), 16, 0, 0)
#define GLD4(src, dst)  __builtin_amdgcn_global_load_lds((gconst_t*)(src), (lds_t*)(dst), 4, 0, 0)
// counted waits (immediates) + sched fence (guide rule #18)
#define WAITV(N) do { asm volatile("s_waitcnt vmcnt(" #N ")" ::: "memory"); \
                      __builtin_amdgcn_sched_barrier(0); } while (0)

__device__ __forceinline__ float tanh_fast(float x) {
  float e = __expf(2.f * x);
  return 1.f - 2.f / (e + 1.f);   // safe at +/-inf
}

// ---------------- k1: blocks [0,256): (b, d-quarter) query projection.
// Blocks [256,320): pack feasibility mask bits -> pmask[b][n].
__global__ __launch_bounds__(256) void k1_query(
    const float* __restrict__ fc, const float* __restrict__ pne,
    const float* __restrict__ vdf, const float* __restrict__ wpcv,
    const float* __restrict__ wpns, const int* __restrict__ mask,
    float* __restrict__ q_ws, float* __restrict__ qw_ws,
    unsigned int* __restrict__ pmask)
{
  const int t = threadIdx.x;
  if (blockIdx.x >= BB * 4) {          // mask-pack blocks
    const int b = blockIdx.x - BB * 4;
    const int* mb = mask + (size_t)(b * MM) * NN;
    for (int n = t; n < NN; n += 256) {
      unsigned int pm = 0;
#pragma unroll
      for (int m = 0; m < MM; ++m) pm |= (mb[m * NN + n] != 0 ? 1u : 0u) << m;
      pmask[b * NN + n] = pm;
    }
    return;
  }
  const int b = blockIdx.x >> 2;
  const int dq = blockIdx.x & 3;
  const int k = t & 15, gid = t >> 4;  // 16 groups of 16 lanes
  __shared__ float qsh[MM][32];

  float cvr[9];
  int curm = -1;
  for (int r = 0; r < 10; ++r) {       // r = m*2 + dhalf
    const int m = r >> 1;
    if (m != curm) {
      curm = m;
      const float* pner = pne + (size_t)(b * MM + m) * DD;
#pragma unroll
      for (int jp = 0; jp < 8; ++jp) cvr[jp] = pner[k + 16 * jp];
      cvr[8] = (k < 3) ? vdf[(b * MM + m) * 3 + k] : 0.f;
    }
    const int dl = (r & 1) * 16 + gid;
    const int d = dq * 32 + dl;
    const float* wrow = wpcv + d * 131;
    float p = 0.f;
#pragma unroll
    for (int jp = 0; jp < 8; ++jp) p = fmaf(cvr[jp], wrow[k + 16 * jp], p);
    if (k < 3) p = fmaf(cvr[8], wrow[128 + k], p);
    p += __shfl_xor(p, 1); p += __shfl_xor(p, 2);
    p += __shfl_xor(p, 4); p += __shfl_xor(p, 8);
    if (k == 0) {
      const float q = 0.25f * (p + fc[b * DD + d]);   // fold 1/sqrt(KS)
      qsh[m][dl] = q;
      q_ws[(size_t)(b * MM + m) * DD + d] = q;
    }
  }
  __syncthreads();
  if (t < 80) {
    const int hh = t / 40;             // 0/1 within this quarter
    const int r = t - hh * 40, m = r >> 3, f = r & 7;
    const int h = dq * 2 + hh;
    float acc = 0.f;
#pragma unroll
    for (int kk = 0; kk < KSZ; ++kk)
      acc = fmaf(qsh[m][hh * 16 + kk], wpns[(DD + h * KSZ + kk) * 8 + f], acc);
    qw_ws[(b * HH + h) * 40 + m * 8 + f] = acc;
  }
}

// ---------------- k2: per (b,h). TRIPLE-buffered global_load_lds pipeline,
// counted vmcnt (never drained to 0 mid-loop) so the HBM pipe stays full
// across tile boundaries. 512 blocks x 512 thr (1 block/CU, 112 KB LDS).
// Wave w issues segs {8j+w} per stage: Sw = 5 (w<6) or 4 (w>=6).
// Consume tile t with t+1,t+2 in flight: wait vmcnt(2*Sw); barrier makes all
// waves' tile-t segs visible. bid = h*64+b -> xcd = b%8.
__global__ __launch_bounds__(512, 2) void k2_attn(
    const float* __restrict__ ndf, const float* __restrict__ gV,
    const float* __restrict__ gK, const unsigned int* __restrict__ pmask,
    const float* __restrict__ q_ws, const float* __restrict__ qw_ws,
    float* __restrict__ part)
{
  const int bid = blockIdx.x;          // h*64 + b
  const int b = bid & 63;
  const int h = bid >> 6;
  const int t = threadIdx.x;
  const int w = t >> 6, lane = t & 63;
  const int k = t & 3, g = t >> 2;     // 128 groups of 4 lanes; n = g

  __shared__ __align__(16) char smem[3][K2_BUF];
  __shared__ float redh[8][MM][KSZ];
  __shared__ float redaf[8][MM][8];
  __shared__ float reds[8];

  const char* gkrow = (const char*)gK + (size_t)(h * BB + b) * (NN * 64);
  const char* gvrow = (const char*)gV + (size_t)(h * BB + b) * (NN * 64);
  const char* pmrow = (const char*)pmask + (size_t)b * (NN * 4);
  const char* ndrow0 = (const char*)ndf + (size_t)(b * MM) * (NN * 32);

  // stage tile tt into buffer bb (38 segs over 8 waves)
  auto stage = [&](int tt, int bb) {
    char* base = smem[bb];
#pragma unroll
    for (int j = 0; j < 5; ++j) {
      const int seg = 8 * j + w;
      if (seg >= 38) continue;
      if (seg < 16) {                  // K (0..7) / V (8..15): 8000B/tile
        const int s = seg & 7;
        int off = tt * 8000 + s * 1024;
        if (off > NN * 64 - 1024) off = NN * 64 - 1024;   // row-local clamp
        const char* srow = (seg < 8) ? gkrow : gvrow;
        const int roff = (seg < 8) ? K2_KOFF : K2_VOFF;
        GLD16(srow + off + lane * 16, base + roff + (off - tt * 8000));
      } else if (seg < 36) {           // ndf: 5 rows x 4000B/tile
        const int rel = seg - 16, m = rel >> 2, q = rel & 3;
        int off = tt * 4000 + q * 1024;
        if (off > NN * 32 - 1024) off = NN * 32 - 1024;
        GLD16(ndrow0 + (size_t)m * (NN * 32) + off + lane * 16,
              base + K2_NOFF + m * 4096 + (off - tt * 4000));
      } else {                         // pmask: 500B/tile, 2 segs of 256B
        const int i4 = seg - 36;
        int off = tt * 500 + i4 * 256;
        if (off > NN * 4 - 256) off = NN * 4 - 256;
        GLD4(pmrow + off + lane * 4, base + K2_POFF + (off - tt * 500));
      }
    }
  };

  float4 qr[MM];
  float2 qw[MM];
#pragma unroll
  for (int m = 0; m < MM; ++m) {
    qr[m] = *(const float4*)(q_ws + (size_t)(b * MM + m) * DD + h * KSZ + 4 * k);
    qw[m] = *(const float2*)(qw_ws + (b * HH + h) * 40 + m * 8 + 2 * k);
  }

  float4 ha[MM] = {};
  float2 af[MM] = {};
  float ls = 0.f;

  stage(0, 0); stage(1, 1); stage(2, 2);   // prefetch depth 2

  for (int tt = 0; tt < NT; ++tt) {
    // wait only for MY tile-tt segs (keep t+1, t+2 in flight)
    if (w < 6) {
      if (tt <= 5) WAITV(10); else if (tt == 6) WAITV(5); else WAITV(0);
    } else {
      if (tt <= 5) WAITV(8); else if (tt == 6) WAITV(4); else WAITV(0);
    }
    __builtin_amdgcn_s_barrier();      // now ALL waves' tile-tt data visible

    const char* base = smem[tt % 3];
    if (g < TN) {
      const int n = g;
      const float4 kv = *(const float4*)(base + K2_KOFF + n * 64 + k * 16);
      const float4 vv = *(const float4*)(base + K2_VOFF + n * 64 + k * 16);
      const unsigned int pm = *(const unsigned int*)(base + K2_POFF + n * 4);
      float2 nd[MM];
#pragma unroll
      for (int m = 0; m < MM; ++m)
        nd[m] = *(const float2*)(base + K2_NOFF + m * 4096 + n * 32 + k * 8);
#pragma unroll
      for (int m = 0; m < MM; ++m) {
        float p = kv.x * qr[m].x + kv.y * qr[m].y
                + kv.z * qr[m].z + kv.w * qr[m].w
                + nd[m].x * qw[m].x + nd[m].y * qw[m].y;
        p += __shfl_xor(p, 1); p += __shfl_xor(p, 2);
        const float e = ((pm >> m) & 1u) ? __expf(p) : 0.f;
        ha[m].x = fmaf(e, vv.x, ha[m].x);
        ha[m].y = fmaf(e, vv.y, ha[m].y);
        ha[m].z = fmaf(e, vv.z, ha[m].z);
        ha[m].w = fmaf(e, vv.w, ha[m].w);
        af[m].x = fmaf(e, nd[m].x, af[m].x);
        af[m].y = fmaf(e, nd[m].y, af[m].y);
        ls += e;
      }
    }
    __builtin_amdgcn_s_barrier();      // all waves done reading buf[tt%3]
    if (tt + 3 < NT) stage(tt + 3, tt % 3);
  }

  // wave butterfly across the 16 groups (k-slot preserved by xor>=4)
#pragma unroll
  for (int off = 4; off <= 32; off <<= 1) {
#pragma unroll
    for (int m = 0; m < MM; ++m) {
      ha[m].x += __shfl_xor(ha[m].x, off);
      ha[m].y += __shfl_xor(ha[m].y, off);
      ha[m].z += __shfl_xor(ha[m].z, off);
      ha[m].w += __shfl_xor(ha[m].w, off);
      af[m].x += __shfl_xor(af[m].x, off);
      af[m].y += __shfl_xor(af[m].y, off);
    }
    ls += __shfl_xor(ls, off);
  }
  if (lane < 4) {
#pragma unroll
    for (int m = 0; m < MM; ++m) {
      *(float4*)(&redh[w][m][4 * k]) = ha[m];
      *(float2*)(&redaf[w][m][2 * k]) = af[m];
    }
    if (k == 0) reds[w] = ls;
  }
  __syncthreads();
  float* P = part + (size_t)(b * HH + h) * 128;
  if (t < 80) {
    const int m = t >> 4, kk = t & 15;
    float s = 0.f;
#pragma unroll
    for (int ww = 0; ww < 8; ++ww) s += redh[ww][m][kk];
    P[t] = s;
  } else if (t < 120) {
    const int r = t - 80, m = r >> 3, f = r & 7;
    float s = 0.f;
#pragma unroll
    for (int ww = 0; ww < 8; ++ww) s += redaf[ww][m][f];
    P[80 + r] = s;
  } else if (t == 120) {
    float s = 0.f;
#pragma unroll
    for (int ww = 0; ww < 8; ++ww) s += reds[ww];
    P[120] = s;
  }
}

// ---------------- k3: per (b,chunk). Fused: combine records -> conc -> fq,fw
// then streaming logits -> e-values. part: one 128-float record per (b,h).
__global__ __launch_bounds__(512) void k3_logits(
    const float* __restrict__ ndf, const float* __restrict__ lK,
    const unsigned int* __restrict__ pmask, const float* __restrict__ part,
    const float* __restrict__ wpns, const float* __restrict__ po,
    float* __restrict__ out, float* __restrict__ stats)
{
  const int b = blockIdx.x >> 3;
  const int c = blockIdx.x & 7;
  const int t = threadIdx.x;

  __shared__ float pos[DD][129];   // stride 129: conflict-free column reads
  __shared__ float rgs[HH];
  __shared__ float afs[HH][MM][8];
  __shared__ float cs[MM][DD];
  __shared__ float fqs[MM][DD];
  __shared__ float fw[MM][8];
  __shared__ float wred[8];

  for (int i = t; i < DD * DD / 4; i += 512) {
    const float4 v = ((const float4*)po)[i];
    const int r = (i * 4) >> 7, cc = (i * 4) & 127;
    pos[r][cc] = v.x; pos[r][cc + 1] = v.y; pos[r][cc + 2] = v.z; pos[r][cc + 3] = v.w;
  }
  const float* pb = part + (size_t)b * HH * 128;
  if (t < HH) rgs[t] = 1.f / pb[t * 128 + 120];
  if (t < HH * MM * 8) {
    const int h = t / 40, r = t % 40;
    afs[h][r >> 3][r & 7] = pb[h * 128 + 80 + r];
  }
  __syncthreads();
  for (int idx = t; idx < MM * DD; idx += 512) {
    const int m = idx >> 7, d = idx & 127, h = d >> 4;
    const float a = pb[h * 128 + m * 16 + (d & 15)];
    float cf = 0.f;
#pragma unroll
    for (int f = 0; f < 8; ++f) cf = fmaf(wpns[d * 8 + f], afs[h][m][f], cf);
    cs[m][d] = (a + cf) * rgs[h];
  }
  __syncthreads();
  for (int idx = t; idx < MM * DD; idx += 512) {
    const int m = idx >> 7, d = idx & 127;
    float acc = 0.f;
#pragma unroll 8
    for (int j = 0; j < DD; ++j) acc = fmaf(cs[m][j], pos[d][j], acc);
    fqs[m][d] = acc * INV_SQRT_D;
  }
  __syncthreads();
  if (t < MM * 8) {
    const int m = t >> 3, f = t & 7;
    float acc = 0.f;
#pragma unroll 16
    for (int d = 0; d < DD; ++d) acc = fmaf(fqs[m][d], wpns[(2 * DD + d) * 8 + f], acc);
    fw[m][f] = acc;
  }
  __syncthreads();

  // ---- streaming logits (16-lane shfl-dot, direct exp)
  const int k = t & 15, gid = t >> 4;   // 32 groups of 16 lanes
  const int n0 = c * CH3;
  float4 fqr[MM][2];
  float fwr[MM];
#pragma unroll
  for (int m = 0; m < MM; ++m) {
    fqr[m][0] = *(const float4*)(&fqs[m][8 * k]);
    fqr[m][1] = *(const float4*)(&fqs[m][8 * k + 4]);
    fwr[m] = fw[m][k & 7];
  }
  float lsum = 0.f;

#pragma unroll
  for (int i = 0; i < 4; ++i) {
    const int nl = gid + 32 * i;
    const bool valid = (nl < CH3);          // group-uniform
    const int n = n0 + (valid ? nl : 0);
    const unsigned int pm = valid ? pmask[b * NN + n] : 0u;
    const float* lkr = lK + ((size_t)b * NN + n) * DD;
    const float4 l0 = *(const float4*)(lkr + 8 * k);
    const float4 l1 = *(const float4*)(lkr + 8 * k + 4);
    float ndv[MM];
#pragma unroll
    for (int m = 0; m < MM; ++m)
      ndv[m] = (k < 8) ? ndf[((size_t)(b * MM + m) * NN + n) * 8 + k] : 0.f;
#pragma unroll
    for (int m = 0; m < MM; ++m) {
      float p = l0.x * fqr[m][0].x + l0.y * fqr[m][0].y
              + l0.z * fqr[m][0].z + l0.w * fqr[m][0].w
              + l1.x * fqr[m][1].x + l1.y * fqr[m][1].y
              + l1.z * fqr[m][1].z + l1.w * fqr[m][1].w
              + ndv[m] * fwr[m];
      p += __shfl_xor(p, 1); p += __shfl_xor(p, 2);
      p += __shfl_xor(p, 4); p += __shfl_xor(p, 8);
      const float e = ((pm >> m) & 1u) ? __expf(tanh_fast(p) * 10.f) : 0.f;
      if (valid) {
        lsum += e;
        if (k == 0) out[(size_t)(b * MM + m) * NN + n] = e;
      }
    }
  }
  lsum += __shfl_xor(lsum, 16);
  lsum += __shfl_xor(lsum, 32);
  if ((t & 63) == 0) wred[t >> 6] = lsum;
  __syncthreads();
  if (t == 0) {
    float s = 0.f;
#pragma unroll
    for (int w2 = 0; w2 < 8; ++w2) s += wred[w2];
    stats[b * NC3 + c] = s;
  }
}

// ---------------- k4: per (b,m) scale row by 1/sum
__global__ __launch_bounds__(256) void k4_probs(
    const float* __restrict__ stats, float* __restrict__ out)
{
  const int bm = blockIdx.x;
  const int b = bm / MM;
  const int t = threadIdx.x;
  float s = 0.f;
#pragma unroll
  for (int c = 0; c < NC3; ++c) s += stats[b * NC3 + c];
  const float scale = 1.f / s;
  if (t < 250) {
    float4* p = (float4*)(out + (size_t)bm * NN);
    float4 v = p[t];
    v.x *= scale; v.y *= scale; v.z *= scale; v.w *= scale;
    p[t] = v;
  }
}

extern "C" void kernel_launch(void* const* d_in, const int* in_sizes, int n_in,
                              void* d_out, int out_size, void* d_ws, size_t ws_size,
                              hipStream_t stream) {
  // d_in[0] = node_embeddings: dead input, never read.
  const float* fc   = (const float*)d_in[1];
  const float* pne  = (const float*)d_in[2];
  const float* ndf  = (const float*)d_in[3];
  const float* vdf  = (const float*)d_in[4];
  const float* gV   = (const float*)d_in[5];
  const float* gK   = (const float*)d_in[6];
  const float* lK   = (const float*)d_in[7];
  const int*   mask = (const int*)d_in[8];
  const float* wpcv = (const float*)d_in[9];
  const float* wpns = (const float*)d_in[10];
  const float* po   = (const float*)d_in[11];

  float* q_ws  = (float*)d_ws;                        // 40960
  float* qw_ws = q_ws + BB * MM * DD;                 // 20480
  float* part  = qw_ws + BB * HH * 40;                // 64*8*128 = 65536
  float* stats = part + (size_t)BB * HH * 128;        // 512
  unsigned int* pmask = (unsigned int*)(stats + BB * NC3);  // 64000 u32
  float* out   = (float*)d_out;

  k1_query<<<BB * 4 + BB, 256, 0, stream>>>(fc, pne, vdf, wpcv, wpns, mask,
                                            q_ws, qw_ws, pmask);
  k2_attn<<<HH * BB, 512, 0, stream>>>(ndf, gV, gK, pmask, q_ws, qw_ws, part);
  k3_logits<<<BB * NC3, 512, 0, stream>>>(ndf, lK, pmask, part, wpns, po, out, stats);
  k4_probs<<<BB * MM, 256, 0, stream>>>(stats, out);
}